// Round 11
// baseline (177.824 us; speedup 1.0000x reference)
//
#include <hip/hip_runtime.h>

#define B_ 2
#define S_ 2048
#define D_ 1024
#define H_ 16
#define HD_ 64
#define M_ (B_*S_)      // 4096
#define N_QKV (3*D_)    // 3072

typedef __attribute__((ext_vector_type(8))) short short8;
typedef __attribute__((ext_vector_type(4))) float floatx4;

__device__ __forceinline__ float fast_exp2(float x) {
    return __builtin_amdgcn_exp2f(x);   // v_exp_f32
}

__device__ __forceinline__ unsigned short f2b(float f) {
    union { float f; unsigned int u; } v; v.f = f;
    unsigned int u = v.u;
    u += 0x7FFFu + ((u >> 16) & 1u);
    return (unsigned short)(u >> 16);
}
// fast round-to-nearest (no even-tie fix) — used only for P probabilities
__device__ __forceinline__ unsigned short f2b_fast(float f) {
    union { float f; unsigned int u; } v; v.f = f;
    return (unsigned short)((v.u + 0x8000u) >> 16);
}

__device__ __forceinline__ void glds16(const unsigned short* g, unsigned short* lds) {
    __builtin_amdgcn_global_load_lds(
        (const __attribute__((address_space(1))) unsigned int*)g,
        (__attribute__((address_space(3))) unsigned int*)lds, 16, 0, 0);
}

// ---------------- merged prep: cast x -> bf16 | transpose-cast w_qkv, w_proj -------------
// Region-decoded 1D grid: [0,4096) cast, [4096,7168) w_qkv transpose, [7168,8192) w_proj.
__global__ __launch_bounds__(256) void prep_kernel(
    const float* __restrict__ x,      unsigned short* __restrict__ xb,
    const float* __restrict__ w_qkv,  unsigned short* __restrict__ wqkvT,
    const float* __restrict__ w_proj, unsigned short* __restrict__ wprojT)
{
    __shared__ float tile[32][33];
    const int id = blockIdx.x;
    if (id < 4096) {
        const int i = (id * 256 + threadIdx.x) * 4;
        float4 f = *(const float4*)(x + i);
        ushort4 o;
        o.x = f2b(f.x); o.y = f2b(f.y); o.z = f2b(f.z); o.w = f2b(f.w);
        *(ushort4*)(xb + i) = o;
    } else {
        const float* W; unsigned short* Wt; int cols, bx, by;
        if (id < 4096 + 3072) {
            W = w_qkv; Wt = wqkvT; cols = N_QKV;
            const int r = id - 4096; bx = r % 96; by = r / 96;
        } else {
            W = w_proj; Wt = wprojT; cols = D_;
            const int r = id - 7168; bx = r % 32; by = r / 32;
        }
        const int rows = D_;
        const int tx = threadIdx.x & 31, ty = threadIdx.x >> 5;
        const int c0 = bx * 32, r0 = by * 32;
        #pragma unroll
        for (int i = 0; i < 4; ++i)
            tile[ty + i*8][tx] = W[(size_t)(r0 + ty + i*8) * cols + c0 + tx];
        __syncthreads();
        #pragma unroll
        for (int i = 0; i < 4; ++i)
            Wt[(size_t)(c0 + ty + i*8) * rows + r0 + tx] = f2b(tile[tx][ty + i*8]);
    }
}

// ---------------- GEMM 128x128, BK=64, swapped operands (C^T fragments) ----------------
// Pipelined K-loop: syncA (drains prev-iter stage, hidden under prev MFMA);
// ds_read frags; syncB (vmcnt already 0 -> cheap); stage(k+64); MFMA.
// Epilogue: Q/K -> direct ushort4 [s][hd]; V -> LDS-transpose -> 128B-contig Vt rows.
__global__ __launch_bounds__(256, 3) void gemm_bt_kernel(
    const unsigned short* __restrict__ A,
    const unsigned short* __restrict__ Bt,
    const float* __restrict__ bias,
    unsigned short* __restrict__ q,
    unsigned short* __restrict__ k_,
    unsigned short* __restrict__ vt,
    int Kdim)
{
    __shared__ unsigned short SMEM[128*136];   // 34.8 KB; loop uses first 32 KB
    unsigned short* As = SMEM;                 // [128][64] shorts
    unsigned short* Bs = SMEM + 128*64;        // [128][64] shorts

    const int t = threadIdx.x;
    const int lane = t & 63;
    const int w = t >> 6;
    const int wm = w >> 1, wn = w & 1;
    const int quad = lane >> 4, l15 = lane & 15;
    const int bm = blockIdx.y, bn = blockIdx.x;

    const int sr32 = t >> 3;
    const int gch  = (t & 7) ^ (sr32 & 7);

    const unsigned short* gA = A  + (size_t)(bm*128 + sr32) * Kdim + gch*8;
    const unsigned short* gB = Bt + (size_t)(bn*128 + sr32) * Kdim + gch*8;
    const size_t rstep = (size_t)32 * Kdim;

    unsigned short* lA = As + (w*8)*64;
    unsigned short* lB = Bs + (w*8)*64;

    const int swz = (l15 & 7);

    auto stage_g = [&](int kk) {
        #pragma unroll
        for (int c = 0; c < 4; ++c) {
            glds16(gA + c*rstep + kk, lA + c*2048);
            glds16(gB + c*rstep + kk, lB + c*2048);
        }
    };

    floatx4 acc[4][4];
    #pragma unroll
    for (int i = 0; i < 4; ++i)
        #pragma unroll
        for (int j = 0; j < 4; ++j)
            acc[i][j] = (floatx4){0.f, 0.f, 0.f, 0.f};

    stage_g(0);
    for (int k0 = 0; k0 < Kdim; k0 += 64) {
        __syncthreads();
        short8 an[4][2], am[4][2];
        #pragma unroll
        for (int i = 0; i < 4; ++i)
            #pragma unroll
            for (int kk = 0; kk < 2; ++kk) {
                const int coff = ((quad + 4*kk) ^ swz) * 8;
                an[i][kk] = *(const short8*)&Bs[(wn*64 + i*16 + l15)*64 + coff];
                am[i][kk] = *(const short8*)&As[(wm*64 + i*16 + l15)*64 + coff];
            }
        __syncthreads();
        if (k0 + 64 < Kdim) stage_g(k0 + 64);
        #pragma unroll
        for (int kk = 0; kk < 2; ++kk)
            #pragma unroll
            for (int i = 0; i < 4; ++i)
                #pragma unroll
                for (int j = 0; j < 4; ++j)
                    acc[i][j] = __builtin_amdgcn_mfma_f32_16x16x32_bf16(an[i][kk], am[j][kk], acc[i][j], 0, 0, 0);
    }

    const float QSCALE = 0.18033688011112042f;   // 0.125 * log2(e)
    const int which = bn >> 3;                   // 0=Q, 1=K, 2=V (block-uniform)
    const int hcol  = (bn & 7)*2 + wn;           // head index
    const int b     = bm >> 4;
    const int sbase0 = (bm & 15)*128;
    const int sbase  = sbase0 + wm*64;

    if (which == 2) {
        // ---- V: LDS transpose -> coalesced Vt[bh][hd][s] rows ----
        unsigned short (*L)[136] = (unsigned short (*)[136])SMEM;
        #pragma unroll
        for (int i = 0; i < 4; ++i) {
            float4 bias4 = *(const float4*)&bias[bn*128 + wn*64 + i*16 + quad*4];
            const int n0 = wn*64 + i*16 + quad*4;
            #pragma unroll
            for (int j = 0; j < 4; ++j) {
                const int m = wm*64 + j*16 + l15;
                L[n0+0][m] = f2b(acc[i][j][0] + bias4.x);
                L[n0+1][m] = f2b(acc[i][j][1] + bias4.y);
                L[n0+2][m] = f2b(acc[i][j][2] + bias4.z);
                L[n0+3][m] = f2b(acc[i][j][3] + bias4.w);
            }
        }
        __syncthreads();
        const int r = t >> 1, half = t & 1;
        const int hcr = (bn & 7)*2 + (r >> 6);
        const int hdr = r & 63;
        unsigned short* dst = &vt[(((size_t)(b*H_ + hcr))*HD_ + hdr)*S_ + sbase0 + half*64];
        const unsigned short* srcL = &L[r][half*64];
        #pragma unroll
        for (int c = 0; c < 8; ++c)
            *(uint4*)&dst[c*8] = *(const uint4*)&srcL[c*8];
    } else {
        #pragma unroll
        for (int i = 0; i < 4; ++i) {
            float4 bias4 = *(const float4*)&bias[bn*128 + wn*64 + i*16 + quad*4];
            const int hd0 = i*16 + quad*4;
            #pragma unroll
            for (int j = 0; j < 4; ++j) {
                const int srow = sbase + j*16 + l15;
                float v0 = acc[i][j][0] + bias4.x;
                float v1 = acc[i][j][1] + bias4.y;
                float v2 = acc[i][j][2] + bias4.z;
                float v3 = acc[i][j][3] + bias4.w;
                if (which == 0) {
                    v0 *= QSCALE; v1 *= QSCALE; v2 *= QSCALE; v3 *= QSCALE;
                    ushort4 o; o.x = f2b(v0); o.y = f2b(v1); o.z = f2b(v2); o.w = f2b(v3);
                    *(ushort4*)&q[((size_t)(b*H_ + hcol) * S_ + srow) * HD_ + hd0] = o;
                } else {
                    ushort4 o; o.x = f2b(v0); o.y = f2b(v1); o.z = f2b(v2); o.w = f2b(v3);
                    *(ushort4*)&k_[((size_t)(b*H_ + hcol) * S_ + srow) * HD_ + hd0] = o;
                }
            }
        }
    }
}

// ---------------- GEMM 128x64 (proj), BK=64, swapped operands, float4 out ----------------
__global__ __launch_bounds__(256, 2) void gemm_bt64_kernel(
    const unsigned short* __restrict__ A,
    const unsigned short* __restrict__ Bt,
    const float* __restrict__ bias,
    float* __restrict__ outf,
    int Ndim, int Kdim)
{
    __shared__ unsigned short As[128*64];   // 16 KB
    __shared__ unsigned short Bs[64*64];    // 8 KB

    const int t = threadIdx.x;
    const int lane = t & 63;
    const int w = t >> 6;
    const int quad = lane >> 4, l15 = lane & 15;
    const int bm = blockIdx.y, bn = blockIdx.x;

    const int sr32 = t >> 3;
    const int gch  = (t & 7) ^ (sr32 & 7);

    const unsigned short* gA = A  + (size_t)(bm*128 + sr32) * Kdim + gch*8;
    const unsigned short* gB = Bt + (size_t)(bn*64  + sr32) * Kdim + gch*8;
    const size_t rstep = (size_t)32 * Kdim;

    unsigned short* lA = As + (w*8)*64;
    unsigned short* lB = Bs + (w*8)*64;

    const int swz = (l15 & 7);

    auto stage_g = [&](int kk) {
        #pragma unroll
        for (int c = 0; c < 4; ++c)
            glds16(gA + c*rstep + kk, lA + c*2048);
        #pragma unroll
        for (int c = 0; c < 2; ++c)
            glds16(gB + c*rstep + kk, lB + c*2048);
    };

    floatx4 acc[4][2];
    #pragma unroll
    for (int i = 0; i < 4; ++i)
        #pragma unroll
        for (int j = 0; j < 2; ++j)
            acc[i][j] = (floatx4){0.f, 0.f, 0.f, 0.f};

    stage_g(0);
    for (int k0 = 0; k0 < Kdim; k0 += 64) {
        __syncthreads();
        short8 an[4][2], am[2][2];
        #pragma unroll
        for (int kk = 0; kk < 2; ++kk) {
            const int coff = ((quad + 4*kk) ^ swz) * 8;
            #pragma unroll
            for (int i = 0; i < 4; ++i)
                an[i][kk] = *(const short8*)&Bs[(i*16 + l15)*64 + coff];
            #pragma unroll
            for (int j = 0; j < 2; ++j)
                am[j][kk] = *(const short8*)&As[(w*32 + j*16 + l15)*64 + coff];
        }
        __syncthreads();
        if (k0 + 64 < Kdim) stage_g(k0 + 64);
        #pragma unroll
        for (int kk = 0; kk < 2; ++kk)
            #pragma unroll
            for (int i = 0; i < 4; ++i)
                #pragma unroll
                for (int j = 0; j < 2; ++j)
                    acc[i][j] = __builtin_amdgcn_mfma_f32_16x16x32_bf16(an[i][kk], am[j][kk], acc[i][j], 0, 0, 0);
    }

    #pragma unroll
    for (int i = 0; i < 4; ++i) {
        float4 bias4 = *(const float4*)&bias[bn*64 + i*16 + quad*4];
        #pragma unroll
        for (int j = 0; j < 2; ++j) {
            const int gm = bm*128 + w*32 + j*16 + l15;
            float4 o;
            o.x = acc[i][j][0] + bias4.x;
            o.y = acc[i][j][1] + bias4.y;
            o.z = acc[i][j][2] + bias4.z;
            o.w = acc[i][j][3] + bias4.w;
            *(float4*)&outf[(size_t)gm * Ndim + bn*64 + i*16 + quad*4] = o;
        }
    }
}

// ---------------- flash attention: 512 x 256-thr blocks, 2 q-groups per wave ----------
// Block owns a 128-row q-chunk c (of 16 per bh); wave w handles rows c*128+w*16 (group0)
// and c*128+64+w*16 (group1). Key tiles 0..2c+1 staged ONCE and consumed by both groups
// -> staging passes/barriers nearly halved vs 64-row chunks (272 vs 528 per bh), and
// each staged tile feeds 32 MFMA instead of 16. Group0 diag at j=2c (skips j=2c+1);
// group1 diag at j=2c+1. XCD-preserving: bh = blk & 31 (head's blocks stride-32 ->
// one XCD -> K/V L2-resident); heavy chunks first (c = 15 - blk>>5) for LPT balance.
__global__ __launch_bounds__(256, 3) void attn_kernel(
    const unsigned short* __restrict__ Q,
    const unsigned short* __restrict__ K,
    const unsigned short* __restrict__ Vt,
    unsigned short* __restrict__ ctx)
{
    __shared__ unsigned short KVs[2][2][64*64];   // [buf][K/V][row*64+col]  32 KB
    __shared__ unsigned short Pt[4][2][16][72];   // [wave][group][q][key]   18.4 KB

    const int t = threadIdx.x;
    const int lane = t & 63, w = t >> 6;          // wave 0..3
    const int quad = lane >> 4, l15 = lane & 15;
    const int bh = blockIdx.x & 31;               // head (stride-32 -> one XCD per head)
    const int c  = 15 - (blockIdx.x >> 5);        // 128-row q-chunk, heavy first
    const int jmax = 2*c + 1;                     // last key tile (group1 diag)

    const unsigned short* Qh  = Q  + (size_t)bh * S_ * HD_;
    const unsigned short* Kh  = K  + (size_t)bh * S_ * HD_;
    const unsigned short* Vth = Vt + (size_t)bh * HD_ * S_;

    // staging geometry: thread t -> row sr (0..31 per half), chunk sc, XOR swizzle
    const int sr = t >> 3, sc = t & 7;
    const int gch = sc ^ (sr & 7);

    auto stage = [&](int j, int d) {
        unsigned short* kb = &KVs[d][0][0];
        unsigned short* vb = &KVs[d][1][0];
        const unsigned short* gk = Kh  + (size_t)(j*64 + sr)*HD_ + gch*8;
        const unsigned short* gv = Vth + (size_t)sr*S_ + (size_t)j*64 + gch*8;
        glds16(gk,                  kb + (w*8)*64);
        glds16(gk + 32*HD_,         kb + (32 + w*8)*64);
        glds16(gv,                  vb + (w*8)*64);
        glds16(gv + (size_t)32*S_,  vb + (32 + w*8)*64);
    };

    const int q0 = c*128 + w*16;                  // group0 base q-row
    const int q1 = q0 + 64;                       // group1 base q-row

    short8 bq0[2], bq1[2];
    #pragma unroll
    for (int kk = 0; kk < 2; ++kk) {
        bq0[kk] = *(const short8*)&Qh[(size_t)(q0 + l15)*HD_ + kk*32 + quad*8];
        bq1[kk] = *(const short8*)&Qh[(size_t)(q1 + l15)*HD_ + kk*32 + quad*8];
    }

    floatx4 O0[4], O1[4];
    #pragma unroll
    for (int nb = 0; nb < 4; ++nb) {
        O0[nb] = (floatx4){0.f,0.f,0.f,0.f};
        O1[nb] = (floatx4){0.f,0.f,0.f,0.f};
    }
    float l0 = 0.f, l1 = 0.f;

    stage(0, 0);

    for (int j = 0; j <= jmax; ++j) {
        __syncthreads();                          // tile j resident; prev reads done
        if (j < jmax) stage(j+1, (j+1)&1);        // prefetch next tile into other buf
        const int d = j & 1;
        const unsigned short* Ksb = &KVs[d][0][0];
        const unsigned short* Vsb = &KVs[d][1][0];
        const bool do0 = (j <= 2*c);              // group0 skips its post-diag tile

        short8 ak[4][2], av[4][2];
        #pragma unroll
        for (int nb = 0; nb < 4; ++nb)
            #pragma unroll
            for (int kk = 0; kk < 2; ++kk) {
                int off = (nb*16 + l15)*64 + (((quad + 4*kk) ^ (l15 & 7)) * 8);
                ak[nb][kk] = *(const short8*)&Ksb[off];
                av[nb][kk] = *(const short8*)&Vsb[off];
            }

        // ---- QK^T both groups back-to-back (one long MFMA cluster) ----
        float z0[4][4], z1[4][4];
        __builtin_amdgcn_s_setprio(1);
        if (do0) {
            #pragma unroll
            for (int nb = 0; nb < 4; ++nb) {
                floatx4 cc = (floatx4){0.f,0.f,0.f,0.f};
                cc = __builtin_amdgcn_mfma_f32_16x16x32_bf16(ak[nb][0], bq0[0], cc, 0,0,0);
                cc = __builtin_amdgcn_mfma_f32_16x16x32_bf16(ak[nb][1], bq0[1], cc, 0,0,0);
                #pragma unroll
                for (int r = 0; r < 4; ++r) z0[nb][r] = cc[r];
            }
        }
        #pragma unroll
        for (int nb = 0; nb < 4; ++nb) {
            floatx4 cc = (floatx4){0.f,0.f,0.f,0.f};
            cc = __builtin_amdgcn_mfma_f32_16x16x32_bf16(ak[nb][0], bq1[0], cc, 0,0,0);
            cc = __builtin_amdgcn_mfma_f32_16x16x32_bf16(ak[nb][1], bq1[1], cc, 0,0,0);
            #pragma unroll
            for (int r = 0; r < 4; ++r) z1[nb][r] = cc[r];
        }
        __builtin_amdgcn_s_setprio(0);

        // ---- causal masks (diag tiles only) ----
        if (j == 2*c) {
            const int qg = q0 + l15, koff = j*64;
            #pragma unroll
            for (int nb = 0; nb < 4; ++nb)
                #pragma unroll
                for (int r = 0; r < 4; ++r)
                    if (koff + nb*16 + quad*4 + r > qg) z0[nb][r] = -1e30f;
        }
        if (j == jmax) {
            const int qg = q1 + l15, koff = j*64;
            #pragma unroll
            for (int nb = 0; nb < 4; ++nb)
                #pragma unroll
                for (int r = 0; r < 4; ++r)
                    if (koff + nb*16 + quad*4 + r > qg) z1[nb][r] = -1e30f;
        }

        // ---- exp2 + pack both groups ----
        if (do0) {
            float rs = 0.f;
            #pragma unroll
            for (int nb = 0; nb < 4; ++nb) {
                float p0 = fast_exp2(z0[nb][0]);
                float p1 = fast_exp2(z0[nb][1]);
                float p2 = fast_exp2(z0[nb][2]);
                float p3 = fast_exp2(z0[nb][3]);
                rs += (p0 + p1) + (p2 + p3);
                ushort4 pk;
                pk.x = f2b_fast(p0); pk.y = f2b_fast(p1);
                pk.z = f2b_fast(p2); pk.w = f2b_fast(p3);
                *(ushort4*)&Pt[w][0][l15][nb*16 + quad*4] = pk;
            }
            l0 += rs;
        }
        {
            float rs = 0.f;
            #pragma unroll
            for (int nb = 0; nb < 4; ++nb) {
                float p0 = fast_exp2(z1[nb][0]);
                float p1 = fast_exp2(z1[nb][1]);
                float p2 = fast_exp2(z1[nb][2]);
                float p3 = fast_exp2(z1[nb][3]);
                rs += (p0 + p1) + (p2 + p3);
                ushort4 pk;
                pk.x = f2b_fast(p0); pk.y = f2b_fast(p1);
                pk.z = f2b_fast(p2); pk.w = f2b_fast(p3);
                *(ushort4*)&Pt[w][1][l15][nb*16 + quad*4] = pk;
            }
            l1 += rs;
        }

        // ---- PV both groups back-to-back ----
        __builtin_amdgcn_s_setprio(1);
        if (do0) {
            short8 bp0 = *(const short8*)&Pt[w][0][l15][quad*8];
            short8 bp1 = *(const short8*)&Pt[w][0][l15][32 + quad*8];
            #pragma unroll
            for (int nb = 0; nb < 4; ++nb) {
                O0[nb] = __builtin_amdgcn_mfma_f32_16x16x32_bf16(av[nb][0], bp0, O0[nb], 0,0,0);
                O0[nb] = __builtin_amdgcn_mfma_f32_16x16x32_bf16(av[nb][1], bp1, O0[nb], 0,0,0);
            }
        }
        {
            short8 bp0 = *(const short8*)&Pt[w][1][l15][quad*8];
            short8 bp1 = *(const short8*)&Pt[w][1][l15][32 + quad*8];
            #pragma unroll
            for (int nb = 0; nb < 4; ++nb) {
                O1[nb] = __builtin_amdgcn_mfma_f32_16x16x32_bf16(av[nb][0], bp0, O1[nb], 0,0,0);
                O1[nb] = __builtin_amdgcn_mfma_f32_16x16x32_bf16(av[nb][1], bp1, O1[nb], 0,0,0);
            }
        }
        __builtin_amdgcn_s_setprio(0);
    }

    // epilogue per group: quad-reduce l, normalize, store ctx[b][s=q][h*64+hd]
    const int b = bh >> 4, h = bh & (H_ - 1);
    auto finish = [&](floatx4 (&O)[4], float l_acc, int qbase) {
        l_acc += __shfl_xor(l_acc, 16, 64);
        l_acc += __shfl_xor(l_acc, 32, 64);
        const float inv = 1.f / l_acc;
        const int qg = qbase + l15;
        #pragma unroll
        for (int nb = 0; nb < 4; ++nb) {
            ushort4 o;
            o.x = f2b(O[nb][0] * inv);
            o.y = f2b(O[nb][1] * inv);
            o.z = f2b(O[nb][2] * inv);
            o.w = f2b(O[nb][3] * inv);
            *(ushort4*)&ctx[((size_t)(b*S_ + qg))*D_ + h*HD_ + nb*16 + quad*4] = o;
        }
    };
    finish(O0, l0, q0);
    finish(O1, l1, q1);
}

extern "C" void kernel_launch(void* const* d_in, const int* in_sizes, int n_in,
                              void* d_out, int out_size, void* d_ws, size_t ws_size,
                              hipStream_t stream) {
    const float* x      = (const float*)d_in[0];
    const float* w_qkv  = (const float*)d_in[1];
    const float* b_qkv  = (const float*)d_in[2];
    const float* w_proj = (const float*)d_in[3];
    const float* b_proj = (const float*)d_in[4];
    float* out = (float*)d_out;

    unsigned short* xb     = (unsigned short*)d_ws;                 // [M][D] (reused as ctx)
    unsigned short* wqkvT  = xb     + (size_t)M_ * D_;              // [3D][D]
    unsigned short* wprojT = wqkvT  + (size_t)N_QKV * D_;           // [D][D]
    unsigned short* Qb     = wprojT + (size_t)D_ * D_;              // [BH][S][HD]
    unsigned short* Kb     = Qb     + (size_t)B_*H_*S_*HD_;
    unsigned short* Vb     = Kb     + (size_t)B_*H_*S_*HD_;         // (unused slot)
    unsigned short* Vtb    = Vb     + (size_t)B_*H_*S_*HD_;         // [BH][HD][S]
    unsigned short* ctx    = xb;                                    // alias: xb dead after gemm0

    prep_kernel<<<dim3(8192), dim3(256), 0, stream>>>(x, xb, w_qkv, wqkvT, w_proj, wprojT);

    gemm_bt_kernel<<<dim3(N_QKV/128, M_/128), dim3(256), 0, stream>>>(
        xb, wqkvT, b_qkv, Qb, Kb, Vtb, D_);

    attn_kernel<<<dim3(512), dim3(256), 0, stream>>>(Qb, Kb, Vtb, ctx);

    gemm_bt64_kernel<<<dim3(D_/64, M_/128), dim3(256), 0, stream>>>(
        ctx, wprojT, b_proj, out, D_, D_);
}

// Round 12
// 163.013 us; speedup vs baseline: 1.0909x; 1.0909x over previous
//
#include <hip/hip_runtime.h>

#define B_ 2
#define S_ 2048
#define D_ 1024
#define H_ 16
#define HD_ 64
#define M_ (B_*S_)      // 4096
#define N_QKV (3*D_)    // 3072

typedef __attribute__((ext_vector_type(8))) short short8;
typedef __attribute__((ext_vector_type(4))) float floatx4;

__device__ __forceinline__ float fast_exp2(float x) {
    return __builtin_amdgcn_exp2f(x);   // v_exp_f32
}

__device__ __forceinline__ unsigned short f2b(float f) {
    union { float f; unsigned int u; } v; v.f = f;
    unsigned int u = v.u;
    u += 0x7FFFu + ((u >> 16) & 1u);
    return (unsigned short)(u >> 16);
}
// fast round-to-nearest (no even-tie fix) — used only for P probabilities
__device__ __forceinline__ unsigned short f2b_fast(float f) {
    union { float f; unsigned int u; } v; v.f = f;
    return (unsigned short)((v.u + 0x8000u) >> 16);
}

__device__ __forceinline__ void glds16(const unsigned short* g, unsigned short* lds) {
    __builtin_amdgcn_global_load_lds(
        (const __attribute__((address_space(1))) unsigned int*)g,
        (__attribute__((address_space(3))) unsigned int*)lds, 16, 0, 0);
}

// ---------------- merged prep: cast x -> bf16 | transpose-cast w_qkv, w_proj -------------
// Region-decoded 1D grid: [0,4096) cast, [4096,7168) w_qkv transpose, [7168,8192) w_proj.
__global__ __launch_bounds__(256) void prep_kernel(
    const float* __restrict__ x,      unsigned short* __restrict__ xb,
    const float* __restrict__ w_qkv,  unsigned short* __restrict__ wqkvT,
    const float* __restrict__ w_proj, unsigned short* __restrict__ wprojT)
{
    __shared__ float tile[32][33];
    const int id = blockIdx.x;
    if (id < 4096) {
        const int i = (id * 256 + threadIdx.x) * 4;
        float4 f = *(const float4*)(x + i);
        ushort4 o;
        o.x = f2b(f.x); o.y = f2b(f.y); o.z = f2b(f.z); o.w = f2b(f.w);
        *(ushort4*)(xb + i) = o;
    } else {
        const float* W; unsigned short* Wt; int cols, bx, by;
        if (id < 4096 + 3072) {
            W = w_qkv; Wt = wqkvT; cols = N_QKV;
            const int r = id - 4096; bx = r % 96; by = r / 96;
        } else {
            W = w_proj; Wt = wprojT; cols = D_;
            const int r = id - 7168; bx = r % 32; by = r / 32;
        }
        const int rows = D_;
        const int tx = threadIdx.x & 31, ty = threadIdx.x >> 5;
        const int c0 = bx * 32, r0 = by * 32;
        #pragma unroll
        for (int i = 0; i < 4; ++i)
            tile[ty + i*8][tx] = W[(size_t)(r0 + ty + i*8) * cols + c0 + tx];
        __syncthreads();
        #pragma unroll
        for (int i = 0; i < 4; ++i)
            Wt[(size_t)(c0 + ty + i*8) * rows + r0 + tx] = f2b(tile[tx][ty + i*8]);
    }
}

// ---------------- GEMM 128x128, BK=64, swapped operands (C^T fragments) ----------------
// Pipelined K-loop: syncA (drains prev-iter stage, hidden under prev MFMA);
// ds_read frags; syncB (vmcnt already 0 -> cheap); stage(k+64); MFMA.
// Epilogue: Q/K -> direct ushort4 [s][hd]; V -> LDS-transpose -> 128B-contig Vt rows.
__global__ __launch_bounds__(256, 3) void gemm_bt_kernel(
    const unsigned short* __restrict__ A,
    const unsigned short* __restrict__ Bt,
    const float* __restrict__ bias,
    unsigned short* __restrict__ q,
    unsigned short* __restrict__ k_,
    unsigned short* __restrict__ vt,
    int Kdim)
{
    __shared__ unsigned short SMEM[128*136];   // 34.8 KB; loop uses first 32 KB
    unsigned short* As = SMEM;                 // [128][64] shorts
    unsigned short* Bs = SMEM + 128*64;        // [128][64] shorts

    const int t = threadIdx.x;
    const int lane = t & 63;
    const int w = t >> 6;
    const int wm = w >> 1, wn = w & 1;
    const int quad = lane >> 4, l15 = lane & 15;
    const int bm = blockIdx.y, bn = blockIdx.x;

    const int sr32 = t >> 3;
    const int gch  = (t & 7) ^ (sr32 & 7);

    const unsigned short* gA = A  + (size_t)(bm*128 + sr32) * Kdim + gch*8;
    const unsigned short* gB = Bt + (size_t)(bn*128 + sr32) * Kdim + gch*8;
    const size_t rstep = (size_t)32 * Kdim;

    unsigned short* lA = As + (w*8)*64;
    unsigned short* lB = Bs + (w*8)*64;

    const int swz = (l15 & 7);

    auto stage_g = [&](int kk) {
        #pragma unroll
        for (int c = 0; c < 4; ++c) {
            glds16(gA + c*rstep + kk, lA + c*2048);
            glds16(gB + c*rstep + kk, lB + c*2048);
        }
    };

    floatx4 acc[4][4];
    #pragma unroll
    for (int i = 0; i < 4; ++i)
        #pragma unroll
        for (int j = 0; j < 4; ++j)
            acc[i][j] = (floatx4){0.f, 0.f, 0.f, 0.f};

    stage_g(0);
    for (int k0 = 0; k0 < Kdim; k0 += 64) {
        __syncthreads();
        short8 an[4][2], am[4][2];
        #pragma unroll
        for (int i = 0; i < 4; ++i)
            #pragma unroll
            for (int kk = 0; kk < 2; ++kk) {
                const int coff = ((quad + 4*kk) ^ swz) * 8;
                an[i][kk] = *(const short8*)&Bs[(wn*64 + i*16 + l15)*64 + coff];
                am[i][kk] = *(const short8*)&As[(wm*64 + i*16 + l15)*64 + coff];
            }
        __syncthreads();
        if (k0 + 64 < Kdim) stage_g(k0 + 64);
        #pragma unroll
        for (int kk = 0; kk < 2; ++kk)
            #pragma unroll
            for (int i = 0; i < 4; ++i)
                #pragma unroll
                for (int j = 0; j < 4; ++j)
                    acc[i][j] = __builtin_amdgcn_mfma_f32_16x16x32_bf16(an[i][kk], am[j][kk], acc[i][j], 0, 0, 0);
    }

    const float QSCALE = 0.18033688011112042f;   // 0.125 * log2(e)
    const int which = bn >> 3;                   // 0=Q, 1=K, 2=V (block-uniform)
    const int hcol  = (bn & 7)*2 + wn;           // head index
    const int b     = bm >> 4;
    const int sbase0 = (bm & 15)*128;
    const int sbase  = sbase0 + wm*64;

    if (which == 2) {
        // ---- V: LDS transpose -> coalesced Vt[bh][hd][s] rows ----
        unsigned short (*L)[136] = (unsigned short (*)[136])SMEM;
        #pragma unroll
        for (int i = 0; i < 4; ++i) {
            float4 bias4 = *(const float4*)&bias[bn*128 + wn*64 + i*16 + quad*4];
            const int n0 = wn*64 + i*16 + quad*4;
            #pragma unroll
            for (int j = 0; j < 4; ++j) {
                const int m = wm*64 + j*16 + l15;
                L[n0+0][m] = f2b(acc[i][j][0] + bias4.x);
                L[n0+1][m] = f2b(acc[i][j][1] + bias4.y);
                L[n0+2][m] = f2b(acc[i][j][2] + bias4.z);
                L[n0+3][m] = f2b(acc[i][j][3] + bias4.w);
            }
        }
        __syncthreads();
        const int r = t >> 1, half = t & 1;
        const int hcr = (bn & 7)*2 + (r >> 6);
        const int hdr = r & 63;
        unsigned short* dst = &vt[(((size_t)(b*H_ + hcr))*HD_ + hdr)*S_ + sbase0 + half*64];
        const unsigned short* srcL = &L[r][half*64];
        #pragma unroll
        for (int c = 0; c < 8; ++c)
            *(uint4*)&dst[c*8] = *(const uint4*)&srcL[c*8];
    } else {
        #pragma unroll
        for (int i = 0; i < 4; ++i) {
            float4 bias4 = *(const float4*)&bias[bn*128 + wn*64 + i*16 + quad*4];
            const int hd0 = i*16 + quad*4;
            #pragma unroll
            for (int j = 0; j < 4; ++j) {
                const int srow = sbase + j*16 + l15;
                float v0 = acc[i][j][0] + bias4.x;
                float v1 = acc[i][j][1] + bias4.y;
                float v2 = acc[i][j][2] + bias4.z;
                float v3 = acc[i][j][3] + bias4.w;
                if (which == 0) {
                    v0 *= QSCALE; v1 *= QSCALE; v2 *= QSCALE; v3 *= QSCALE;
                    ushort4 o; o.x = f2b(v0); o.y = f2b(v1); o.z = f2b(v2); o.w = f2b(v3);
                    *(ushort4*)&q[((size_t)(b*H_ + hcol) * S_ + srow) * HD_ + hd0] = o;
                } else {
                    ushort4 o; o.x = f2b(v0); o.y = f2b(v1); o.z = f2b(v2); o.w = f2b(v3);
                    *(ushort4*)&k_[((size_t)(b*H_ + hcol) * S_ + srow) * HD_ + hd0] = o;
                }
            }
        }
    }
}

// ---------------- GEMM 128x64 (proj), BK=64, swapped operands, float4 out ----------------
__global__ __launch_bounds__(256, 2) void gemm_bt64_kernel(
    const unsigned short* __restrict__ A,
    const unsigned short* __restrict__ Bt,
    const float* __restrict__ bias,
    float* __restrict__ outf,
    int Ndim, int Kdim)
{
    __shared__ unsigned short As[128*64];   // 16 KB
    __shared__ unsigned short Bs[64*64];    // 8 KB

    const int t = threadIdx.x;
    const int lane = t & 63;
    const int w = t >> 6;
    const int quad = lane >> 4, l15 = lane & 15;
    const int bm = blockIdx.y, bn = blockIdx.x;

    const int sr32 = t >> 3;
    const int gch  = (t & 7) ^ (sr32 & 7);

    const unsigned short* gA = A  + (size_t)(bm*128 + sr32) * Kdim + gch*8;
    const unsigned short* gB = Bt + (size_t)(bn*64  + sr32) * Kdim + gch*8;
    const size_t rstep = (size_t)32 * Kdim;

    unsigned short* lA = As + (w*8)*64;
    unsigned short* lB = Bs + (w*8)*64;

    const int swz = (l15 & 7);

    auto stage_g = [&](int kk) {
        #pragma unroll
        for (int c = 0; c < 4; ++c)
            glds16(gA + c*rstep + kk, lA + c*2048);
        #pragma unroll
        for (int c = 0; c < 2; ++c)
            glds16(gB + c*rstep + kk, lB + c*2048);
    };

    floatx4 acc[4][2];
    #pragma unroll
    for (int i = 0; i < 4; ++i)
        #pragma unroll
        for (int j = 0; j < 2; ++j)
            acc[i][j] = (floatx4){0.f, 0.f, 0.f, 0.f};

    stage_g(0);
    for (int k0 = 0; k0 < Kdim; k0 += 64) {
        __syncthreads();
        short8 an[4][2], am[2][2];
        #pragma unroll
        for (int kk = 0; kk < 2; ++kk) {
            const int coff = ((quad + 4*kk) ^ swz) * 8;
            #pragma unroll
            for (int i = 0; i < 4; ++i)
                an[i][kk] = *(const short8*)&Bs[(i*16 + l15)*64 + coff];
            #pragma unroll
            for (int j = 0; j < 2; ++j)
                am[j][kk] = *(const short8*)&As[(w*32 + j*16 + l15)*64 + coff];
        }
        __syncthreads();
        if (k0 + 64 < Kdim) stage_g(k0 + 64);
        #pragma unroll
        for (int kk = 0; kk < 2; ++kk)
            #pragma unroll
            for (int i = 0; i < 4; ++i)
                #pragma unroll
                for (int j = 0; j < 2; ++j)
                    acc[i][j] = __builtin_amdgcn_mfma_f32_16x16x32_bf16(an[i][kk], am[j][kk], acc[i][j], 0, 0, 0);
    }

    #pragma unroll
    for (int i = 0; i < 4; ++i) {
        float4 bias4 = *(const float4*)&bias[bn*64 + i*16 + quad*4];
        #pragma unroll
        for (int j = 0; j < 2; ++j) {
            const int gm = bm*128 + w*32 + j*16 + l15;
            float4 o;
            o.x = acc[i][j][0] + bias4.x;
            o.y = acc[i][j][1] + bias4.y;
            o.z = acc[i][j][2] + bias4.z;
            o.w = acc[i][j][3] + bias4.w;
            *(float4*)&outf[(size_t)gm * Ndim + bn*64 + i*16 + quad*4] = o;
        }
    }
}

// ---------------- flash attention: 1024 x 256-thr blocks, 3 blocks/CU ----------------
// One 64-row q-chunk per block; tiles 0..c. XCD-preserving mapping: bh = blk & 31
// (a head's blocks sit at stride 32 -> all on XCD bh%8 -> K/V fetched once, L2-served).
// Heavy chunks first (c = 31 - blk>>5): LPT balancing across the 4x-oversubscribed grid.
// R11 lesson: coarser decompositions (128-row chunks / hand-pairing) lose more to
// imbalance+occupancy than they gain in staging amortization — keep this form.
__global__ __launch_bounds__(256, 3) void attn_kernel(
    const unsigned short* __restrict__ Q,
    const unsigned short* __restrict__ K,
    const unsigned short* __restrict__ Vt,
    unsigned short* __restrict__ ctx)
{
    __shared__ unsigned short KVs[2][2][64*64];   // [buf][K/V][row*64+col]  32 KB
    __shared__ unsigned short Pt[4][16][72];      // [wave][q][key]          9.2 KB

    const int t = threadIdx.x;
    const int lane = t & 63, w = t >> 6;          // wave 0..3
    const int quad = lane >> 4, l15 = lane & 15;
    const int bh = blockIdx.x & 31;               // head (stride-32 -> one XCD per head)
    const int c  = 31 - (blockIdx.x >> 5);        // q-chunk, heavy first

    const unsigned short* Qh  = Q  + (size_t)bh * S_ * HD_;
    const unsigned short* Kh  = K  + (size_t)bh * S_ * HD_;
    const unsigned short* Vth = Vt + (size_t)bh * HD_ * S_;

    // staging geometry: thread t -> row sr (0..31 per half), chunk sc, XOR swizzle
    const int sr = t >> 3, sc = t & 7;
    const int gch = sc ^ (sr & 7);

    auto stage = [&](int j, int d) {
        unsigned short* kb = &KVs[d][0][0];
        unsigned short* vb = &KVs[d][1][0];
        const unsigned short* gk = Kh  + (size_t)(j*64 + sr)*HD_ + gch*8;
        const unsigned short* gv = Vth + (size_t)sr*S_ + (size_t)j*64 + gch*8;
        glds16(gk,                  kb + (w*8)*64);
        glds16(gk + 32*HD_,         kb + (32 + w*8)*64);
        glds16(gv,                  vb + (w*8)*64);
        glds16(gv + (size_t)32*S_,  vb + (32 + w*8)*64);
    };

    const int qc = c*64 + w*16;                   // this wave's q-row base

    short8 bq[2];
    #pragma unroll
    for (int kk = 0; kk < 2; ++kk)
        bq[kk] = *(const short8*)&Qh[(size_t)(qc + l15)*HD_ + kk*32 + quad*8];

    floatx4 O[4];
    #pragma unroll
    for (int nb = 0; nb < 4; ++nb)
        O[nb] = (floatx4){0.f,0.f,0.f,0.f};
    float l_acc = 0.f;

    stage(0, 0);

    for (int j = 0; j <= c; ++j) {
        __syncthreads();                          // tile j resident; prev reads done
        if (j < c) stage(j+1, (j+1)&1);           // prefetch next tile into other buf
        const int d = j & 1;
        const unsigned short* Ksb = &KVs[d][0][0];
        const unsigned short* Vsb = &KVs[d][1][0];

        short8 ak[4][2], av[4][2];
        #pragma unroll
        for (int nb = 0; nb < 4; ++nb)
            #pragma unroll
            for (int kk = 0; kk < 2; ++kk) {
                int off = (nb*16 + l15)*64 + (((quad + 4*kk) ^ (l15 & 7)) * 8);
                ak[nb][kk] = *(const short8*)&Ksb[off];
                av[nb][kk] = *(const short8*)&Vsb[off];
            }

        // ---- S^T = K Q^T (8 MFMA) ----
        float z[4][4];
        __builtin_amdgcn_s_setprio(1);
        #pragma unroll
        for (int nb = 0; nb < 4; ++nb) {
            floatx4 cc = (floatx4){0.f,0.f,0.f,0.f};
            cc = __builtin_amdgcn_mfma_f32_16x16x32_bf16(ak[nb][0], bq[0], cc, 0,0,0);
            cc = __builtin_amdgcn_mfma_f32_16x16x32_bf16(ak[nb][1], bq[1], cc, 0,0,0);
            #pragma unroll
            for (int r = 0; r < 4; ++r) z[nb][r] = cc[r];
        }
        __builtin_amdgcn_s_setprio(0);

        // ---- causal mask (diag tile only) ----
        if (j == c) {
            const int qg = qc + l15, koff = j*64;
            #pragma unroll
            for (int nb = 0; nb < 4; ++nb)
                #pragma unroll
                for (int r = 0; r < 4; ++r)
                    if (koff + nb*16 + quad*4 + r > qg) z[nb][r] = -1e30f;
        }

        // ---- exp2 + pack -> Pt ----
        float rs = 0.f;
        #pragma unroll
        for (int nb = 0; nb < 4; ++nb) {
            float p0 = fast_exp2(z[nb][0]);
            float p1 = fast_exp2(z[nb][1]);
            float p2 = fast_exp2(z[nb][2]);
            float p3 = fast_exp2(z[nb][3]);
            rs += (p0 + p1) + (p2 + p3);
            ushort4 pk;
            pk.x = f2b_fast(p0); pk.y = f2b_fast(p1);
            pk.z = f2b_fast(p2); pk.w = f2b_fast(p3);
            *(ushort4*)&Pt[w][l15][nb*16 + quad*4] = pk;
        }
        l_acc += rs;

        // ---- PV: O^T += V^T P^T (8 MFMA) ----
        short8 bp0 = *(const short8*)&Pt[w][l15][quad*8];
        short8 bp1 = *(const short8*)&Pt[w][l15][32 + quad*8];
        __builtin_amdgcn_s_setprio(1);
        #pragma unroll
        for (int nb = 0; nb < 4; ++nb) {
            O[nb] = __builtin_amdgcn_mfma_f32_16x16x32_bf16(av[nb][0], bp0, O[nb], 0,0,0);
            O[nb] = __builtin_amdgcn_mfma_f32_16x16x32_bf16(av[nb][1], bp1, O[nb], 0,0,0);
        }
        __builtin_amdgcn_s_setprio(0);
    }

    // epilogue: quad-reduce l, normalize, store ctx[b][s=q][h*64+hd]
    const int b = bh >> 4, h = bh & (H_ - 1);
    l_acc += __shfl_xor(l_acc, 16, 64);
    l_acc += __shfl_xor(l_acc, 32, 64);
    const float inv = 1.f / l_acc;
    const int qg = qc + l15;
    #pragma unroll
    for (int nb = 0; nb < 4; ++nb) {
        ushort4 o;
        o.x = f2b(O[nb][0] * inv);
        o.y = f2b(O[nb][1] * inv);
        o.z = f2b(O[nb][2] * inv);
        o.w = f2b(O[nb][3] * inv);
        *(ushort4*)&ctx[((size_t)(b*S_ + qg))*D_ + h*HD_ + nb*16 + quad*4] = o;
    }
}

extern "C" void kernel_launch(void* const* d_in, const int* in_sizes, int n_in,
                              void* d_out, int out_size, void* d_ws, size_t ws_size,
                              hipStream_t stream) {
    const float* x      = (const float*)d_in[0];
    const float* w_qkv  = (const float*)d_in[1];
    const float* b_qkv  = (const float*)d_in[2];
    const float* w_proj = (const float*)d_in[3];
    const float* b_proj = (const float*)d_in[4];
    float* out = (float*)d_out;

    unsigned short* xb     = (unsigned short*)d_ws;                 // [M][D] (reused as ctx)
    unsigned short* wqkvT  = xb     + (size_t)M_ * D_;              // [3D][D]
    unsigned short* wprojT = wqkvT  + (size_t)N_QKV * D_;           // [D][D]
    unsigned short* Qb     = wprojT + (size_t)D_ * D_;              // [BH][S][HD]
    unsigned short* Kb     = Qb     + (size_t)B_*H_*S_*HD_;
    unsigned short* Vb     = Kb     + (size_t)B_*H_*S_*HD_;         // (unused slot)
    unsigned short* Vtb    = Vb     + (size_t)B_*H_*S_*HD_;         // [BH][HD][S]
    unsigned short* ctx    = xb;                                    // alias: xb dead after gemm0

    prep_kernel<<<dim3(8192), dim3(256), 0, stream>>>(x, xb, w_qkv, wqkvT, w_proj, wprojT);

    gemm_bt_kernel<<<dim3(N_QKV/128, M_/128), dim3(256), 0, stream>>>(
        xb, wqkvT, b_qkv, Qb, Kb, Vtb, D_);

    attn_kernel<<<dim3(1024), dim3(256), 0, stream>>>(Qb, Kb, Vtb, ctx);

    gemm_bt64_kernel<<<dim3(D_/64, M_/128), dim3(256), 0, stream>>>(
        ctx, wprojT, b_proj, out, D_, D_);
}